// Round 5
// baseline (464.343 us; speedup 1.0000x reference)
//
#include <hip/hip_runtime.h>

#define KNODES 4096
#define SEQL 32
#define DM 128
#define DFF 512
#define NEDGE 65536
#define NETOT (NEDGE + KNODES)

typedef float f32x4 __attribute__((ext_vector_type(4)));
typedef short s16x8 __attribute__((ext_vector_type(8)));
typedef short s16x4 __attribute__((ext_vector_type(4)));

#define MFMA16(a, b, c) __builtin_amdgcn_mfma_f32_16x16x32_bf16(a, b, c, 0, 0, 0)

__device__ __forceinline__ short f2bf(float f) {
  union { float f; unsigned u; } v; v.f = f;
  unsigned r = (v.u + 0x7FFFu + ((v.u >> 16) & 1u)) >> 16;
  return (short)r;
}

__device__ __forceinline__ float gelu_exact(float v) {
  return 0.5f * v * (1.f + erff(v * 0.70710678118654752440f));
}

// LayerNorm one row-slice: 16 lanes per row, 8 elems per lane.
__device__ __forceinline__ void ln_to_bf16(const float* XF, short* AB,
                                           const float* __restrict__ g,
                                           const float* __restrict__ b,
                                           int r, int cb) {
  const float* xr = XF + r * 132 + cb;
  float v[8]; float s = 0.f, ss = 0.f;
#pragma unroll
  for (int i = 0; i < 8; ++i) { v[i] = xr[i]; s += v[i]; ss += v[i] * v[i]; }
  s += __shfl_xor(s, 1); ss += __shfl_xor(ss, 1);
  s += __shfl_xor(s, 2); ss += __shfl_xor(ss, 2);
  s += __shfl_xor(s, 4); ss += __shfl_xor(ss, 4);
  s += __shfl_xor(s, 8); ss += __shfl_xor(ss, 8);
  const float mean = s * (1.f / 128.f);
  const float var = ss * (1.f / 128.f) - mean * mean;
  const float rs = rsqrtf(var + 1e-5f);
  const float* gp = g + cb; const float* bp = b + cb;
  short o[8];
#pragma unroll
  for (int i = 0; i < 8; ++i) o[i] = f2bf((v[i] - mean) * rs * gp[i] + bp[i]);
  *(s16x8*)(AB + r * 136 + cb) = *(s16x8*)o;
}

// LDS map (bytes), total 53248 -> 3 blocks/CU; 512 thr = 8 waves -> 24 waves/CU.
//  XF @0      fp32 [32][132]; AB/Sf/Pb @16896; Qb @25600; Kb @34304;
//  Fb @25600 (aliases Qb+Kb during FFN); Vt @43008.
__global__ __launch_bounds__(512, 6) void temporal_kernel(
    const float* __restrict__ x,
    const float* __restrict__ ln1_g, const float* __restrict__ ln1_b,
    const short* __restrict__ qkv_wb, const float* __restrict__ qkv_b,
    const short* __restrict__ out_wb, const float* __restrict__ out_b,
    const float* __restrict__ ln2_g, const float* __restrict__ ln2_b,
    const short* __restrict__ ff1_wb, const float* __restrict__ ff1_b,
    const short* __restrict__ ff2_wb, const float* __restrict__ ff2_b,
    const short* __restrict__ gat_wb,
    const float* __restrict__ att_src, const float* __restrict__ att_dst,
    short* __restrict__ h_out, float* __restrict__ as_out, float* __restrict__ ad_out) {
  __shared__ __align__(16) char smem[53248];
  float* XF = (float*)smem;
  short* AB = (short*)(smem + 16896);
  float* Sf = (float*)(smem + 16896);
  short* Pb = (short*)(smem + 21504);
  short* Qb = (short*)(smem + 25600);
  short* Kb = (short*)(smem + 34304);
  short* Fb = (short*)(smem + 25600);
  short* Vt = (short*)(smem + 43008);

  const int t = threadIdx.x;
  const int w = t >> 6;                 // 8 waves
  const int lane = t & 63;
  const int q = lane >> 4, c = lane & 15;
  const int n = blockIdx.x;
  const int r16 = t >> 4, cb8 = (t & 15) * 8;   // LN roles: 16 lanes/row

  // ---- load x -> XF (fp32, 2 float4 per thread)
  {
#pragma unroll
    for (int i = t; i < 1024; i += 512) {
      const int row = i >> 5, c4i = i & 31;
      *(float4*)(XF + row * 132 + c4i * 4) =
          *(const float4*)(x + (size_t)n * (SEQL * DM) + i * 4);
    }
  }
  __syncthreads();

  // ---- LN1 -> AB
  ln_to_bf16(XF, AB, ln1_g, ln1_b, r16, cb8);
  __syncthreads();

  // ---- QKV GEMM: 24 N-tiles, 3 per wave.
  {
    s16x8 a[2][4];
#pragma unroll
    for (int mt = 0; mt < 2; ++mt)
#pragma unroll
      for (int kt = 0; kt < 4; ++kt)
        a[mt][kt] = *(const s16x8*)(AB + (mt * 16 + c) * 136 + kt * 32 + q * 8);
    for (int ii = 0; ii < 3; ++ii) {
      const int n0 = (w * 3 + ii) * 16;
      const short* wp = qkv_wb + (n0 + c) * DM + q * 8;
      s16x8 bf[4];
#pragma unroll
      for (int kt = 0; kt < 4; ++kt) bf[kt] = *(const s16x8*)(wp + kt * 32);
      f32x4 acc0 = {0.f, 0.f, 0.f, 0.f}, acc1 = {0.f, 0.f, 0.f, 0.f};
#pragma unroll
      for (int kt = 0; kt < 4; ++kt) {
        acc0 = MFMA16(a[0][kt], bf[kt], acc0);
        acc1 = MFMA16(a[1][kt], bf[kt], acc1);
      }
      const float bias = qkv_b[n0 + c];
      if (n0 < 128) {            // Q
#pragma unroll
        for (int i = 0; i < 4; ++i) {
          Qb[(q * 4 + i) * 136 + n0 + c] = f2bf(acc0[i] + bias);
          Qb[(16 + q * 4 + i) * 136 + n0 + c] = f2bf(acc1[i] + bias);
        }
      } else if (n0 < 256) {     // K
        const int cc = n0 - 128 + c;
#pragma unroll
        for (int i = 0; i < 4; ++i) {
          Kb[(q * 4 + i) * 136 + cc] = f2bf(acc0[i] + bias);
          Kb[(16 + q * 4 + i) * 136 + cc] = f2bf(acc1[i] + bias);
        }
      } else {                   // V -> Vt transposed
        const int d = n0 - 256 + c;
        s16x4 p0, p1;
#pragma unroll
        for (int i = 0; i < 4; ++i) { p0[i] = f2bf(acc0[i] + bias); p1[i] = f2bf(acc1[i] + bias); }
        *(s16x4*)(Vt + d * 40 + q * 4) = p0;
        *(s16x4*)(Vt + d * 40 + 16 + q * 4) = p1;
      }
    }
  }
  __syncthreads();

  // ---- scores S = Q K^T / sqrt(128). 4 tiles on waves 0-3.
  if (w < 4) {
    const int mt = w & 1, nt = w >> 1;
    s16x8 aq[4], bk[4];
#pragma unroll
    for (int kt = 0; kt < 4; ++kt) {
      aq[kt] = *(const s16x8*)(Qb + (mt * 16 + c) * 136 + kt * 32 + q * 8);
      bk[kt] = *(const s16x8*)(Kb + (nt * 16 + c) * 136 + kt * 32 + q * 8);
    }
    f32x4 acc = {0.f, 0.f, 0.f, 0.f};
#pragma unroll
    for (int kt = 0; kt < 4; ++kt) acc = MFMA16(aq[kt], bk[kt], acc);
#pragma unroll
    for (int i = 0; i < 4; ++i)
      Sf[(mt * 16 + q * 4 + i) * 36 + nt * 16 + c] = acc[i] * 0.08838834764831845f;
  }
  __syncthreads();

  // ---- softmax rows of Sf -> Pb (threads 0..255, 8 lanes/row)
  if (t < 256) {
    const int r8 = t >> 3, c4 = (t & 7) * 4;
    float4 sv = *(const float4*)(Sf + r8 * 36 + c4);
    float mx = fmaxf(fmaxf(sv.x, sv.y), fmaxf(sv.z, sv.w));
    mx = fmaxf(mx, __shfl_xor(mx, 1));
    mx = fmaxf(mx, __shfl_xor(mx, 2));
    mx = fmaxf(mx, __shfl_xor(mx, 4));
    float e0 = expf(sv.x - mx), e1 = expf(sv.y - mx), e2 = expf(sv.z - mx), e3 = expf(sv.w - mx);
    float sum = e0 + e1 + e2 + e3;
    sum += __shfl_xor(sum, 1);
    sum += __shfl_xor(sum, 2);
    sum += __shfl_xor(sum, 4);
    const float inv = 1.f / sum;
    s16x4 pw; pw[0] = f2bf(e0 * inv); pw[1] = f2bf(e1 * inv); pw[2] = f2bf(e2 * inv); pw[3] = f2bf(e3 * inv);
    *(s16x4*)(Pb + r8 * 40 + c4) = pw;
  }
  __syncthreads();

  // ---- attn = P @ V. 1 d-tile per wave -> Qb.
  {
    s16x8 ap0 = *(const s16x8*)(Pb + c * 40 + q * 8);
    s16x8 ap1 = *(const s16x8*)(Pb + (16 + c) * 40 + q * 8);
    const int d0 = w * 16;
    s16x8 bv = *(const s16x8*)(Vt + (d0 + c) * 40 + q * 8);
    f32x4 acc0 = {0.f, 0.f, 0.f, 0.f}, acc1 = {0.f, 0.f, 0.f, 0.f};
    acc0 = MFMA16(ap0, bv, acc0);
    acc1 = MFMA16(ap1, bv, acc1);
#pragma unroll
    for (int i = 0; i < 4; ++i) {
      Qb[(q * 4 + i) * 136 + d0 + c] = f2bf(acc0[i]);
      Qb[(16 + q * 4 + i) * 136 + d0 + c] = f2bf(acc1[i]);
    }
  }
  __syncthreads();

  // ---- proj: XF += attn @ out_w^T + out_b. 1 n-tile per wave.
  {
    s16x8 aa[2][4];
#pragma unroll
    for (int mt = 0; mt < 2; ++mt)
#pragma unroll
      for (int kt = 0; kt < 4; ++kt)
        aa[mt][kt] = *(const s16x8*)(Qb + (mt * 16 + c) * 136 + kt * 32 + q * 8);
    const int n0 = w * 16;
    const short* wp = out_wb + (n0 + c) * DM + q * 8;
    s16x8 bf[4];
#pragma unroll
    for (int kt = 0; kt < 4; ++kt) bf[kt] = *(const s16x8*)(wp + kt * 32);
    f32x4 acc0 = {0.f, 0.f, 0.f, 0.f}, acc1 = {0.f, 0.f, 0.f, 0.f};
#pragma unroll
    for (int kt = 0; kt < 4; ++kt) {
      acc0 = MFMA16(aa[0][kt], bf[kt], acc0);
      acc1 = MFMA16(aa[1][kt], bf[kt], acc1);
    }
    const float bias = out_b[n0 + c];
#pragma unroll
    for (int i = 0; i < 4; ++i) {
      XF[(q * 4 + i) * 132 + n0 + c] += acc0[i] + bias;
      XF[(16 + q * 4 + i) * 132 + n0 + c] += acc1[i] + bias;
    }
  }
  __syncthreads();

  // ---- LN2 -> AB
  ln_to_bf16(XF, AB, ln2_g, ln2_b, r16, cb8);
  __syncthreads();

  // ---- FFN: two 256-col chunks; FFN1 2 tiles/wave, FFN2 1 n-tile/wave.
  {
    s16x8 af[2][4];
#pragma unroll
    for (int mt = 0; mt < 2; ++mt)
#pragma unroll
      for (int kt = 0; kt < 4; ++kt)
        af[mt][kt] = *(const s16x8*)(AB + (mt * 16 + c) * 136 + kt * 32 + q * 8);
    f32x4 facc0 = {0.f, 0.f, 0.f, 0.f}, facc1 = {0.f, 0.f, 0.f, 0.f};

    for (int ch = 0; ch < 2; ++ch) {
#pragma unroll
      for (int ii = 0; ii < 2; ++ii) {
        const int ntl = w * 2 + ii;
        const int n0g = ch * 256 + ntl * 16;
        const short* wp = ff1_wb + (n0g + c) * DM + q * 8;
        s16x8 bf[4];
#pragma unroll
        for (int kt = 0; kt < 4; ++kt) bf[kt] = *(const s16x8*)(wp + kt * 32);
        f32x4 acc0 = {0.f, 0.f, 0.f, 0.f}, acc1 = {0.f, 0.f, 0.f, 0.f};
#pragma unroll
        for (int kt = 0; kt < 4; ++kt) {
          acc0 = MFMA16(af[0][kt], bf[kt], acc0);
          acc1 = MFMA16(af[1][kt], bf[kt], acc1);
        }
        const float bias = ff1_b[n0g + c];
#pragma unroll
        for (int i = 0; i < 4; ++i) {
          Fb[(q * 4 + i) * 264 + ntl * 16 + c] = f2bf(gelu_exact(acc0[i] + bias));
          Fb[(16 + q * 4 + i) * 264 + ntl * 16 + c] = f2bf(gelu_exact(acc1[i] + bias));
        }
      }
      __syncthreads();
      {
        const int n0 = w * 16;
        const short* wp = ff2_wb + (n0 + c) * DFF + ch * 256 + q * 8;
#pragma unroll
        for (int kt = 0; kt < 8; ++kt) {
          s16x8 a0 = *(const s16x8*)(Fb + c * 264 + kt * 32 + q * 8);
          s16x8 a1 = *(const s16x8*)(Fb + (16 + c) * 264 + kt * 32 + q * 8);
          s16x8 bf = *(const s16x8*)(wp + kt * 32);
          facc0 = MFMA16(a0, bf, facc0);
          facc1 = MFMA16(a1, bf, facc1);
        }
      }
      __syncthreads();
    }
    // epilogue fused with xt->bf16: AB = bf16(XF + facc + ff2_b)
    {
      const int n0 = w * 16;
      const float bias = ff2_b[n0 + c];
#pragma unroll
      for (int i = 0; i < 4; ++i) {
        const int r0 = q * 4 + i, r1 = 16 + q * 4 + i;
        AB[r0 * 136 + n0 + c] = f2bf(XF[r0 * 132 + n0 + c] + facc0[i] + bias);
        AB[r1 * 136 + n0 + c] = f2bf(XF[r1 * 132 + n0 + c] + facc1[i] + bias);
      }
    }
  }
  __syncthreads();

  // ---- GAT projection h = xt @ gat_w^T. 1 n-tile per wave.
  {
    s16x8 ag[2][4];
#pragma unroll
    for (int mt = 0; mt < 2; ++mt)
#pragma unroll
      for (int kt = 0; kt < 4; ++kt)
        ag[mt][kt] = *(const s16x8*)(AB + (mt * 16 + c) * 136 + kt * 32 + q * 8);
    const int n0 = w * 16;
    const short* wp = gat_wb + (n0 + c) * DM + q * 8;
    s16x8 bf[4];
#pragma unroll
    for (int kt = 0; kt < 4; ++kt) bf[kt] = *(const s16x8*)(wp + kt * 32);
    f32x4 acc0 = {0.f, 0.f, 0.f, 0.f}, acc1 = {0.f, 0.f, 0.f, 0.f};
#pragma unroll
    for (int kt = 0; kt < 4; ++kt) {
      acc0 = MFMA16(ag[0][kt], bf[kt], acc0);
      acc1 = MFMA16(ag[1][kt], bf[kt], acc1);
    }
#pragma unroll
    for (int i = 0; i < 4; ++i) {
      const int r0 = q * 4 + i, r1 = 16 + q * 4 + i;
      h_out[((size_t)n * SEQL + r0) * DM + n0 + c] = f2bf(acc0[i]);
      h_out[((size_t)n * SEQL + r1) * DM + n0 + c] = f2bf(acc1[i]);
      XF[r0 * 132 + n0 + c] = acc0[i];
      XF[r1 * 132 + n0 + c] = acc1[i];
    }
  }
  __syncthreads();

  // ---- a_s / a_d
  if (t < 64) {
    const int row = t & 31;
    const float* vec = (t < 32) ? att_src : att_dst;
    const float* hr = XF + row * 132;
    float s = 0.f;
#pragma unroll
    for (int d = 0; d < DM; d += 4)
      s += hr[d] * vec[d] + hr[d + 1] * vec[d + 1] + hr[d + 2] * vec[d + 2] + hr[d + 3] * vec[d + 3];
    if (t < 32) as_out[n * SEQL + row] = s;
    else        ad_out[n * SEQL + row] = s;
  }
}

// fp32 -> bf16 weight conversion.
__global__ void cvt_weights(const float* __restrict__ qkv_w, const float* __restrict__ out_w,
                            const float* __restrict__ ff1_w, const float* __restrict__ ff2_w,
                            const float* __restrict__ gat_w, short* __restrict__ wb) {
  const int i = (blockIdx.x * 256 + threadIdx.x) * 4;
  if (i >= 212992) return;
  const float* src; int off;
  if (i < 49152)       { src = qkv_w; off = i; }
  else if (i < 65536)  { src = out_w; off = i - 49152; }
  else if (i < 131072) { src = ff1_w; off = i - 65536; }
  else if (i < 196608) { src = ff2_w; off = i - 131072; }
  else                 { src = gat_w; off = i - 196608; }
  const float4 v = *(const float4*)(src + off);
  s16x4 o; o[0] = f2bf(v.x); o[1] = f2bf(v.y); o[2] = f2bf(v.z); o[3] = f2bf(v.w);
  *(s16x4*)(wb + i) = o;
}

__global__ void zero_counts(int* counts) {
  int i = blockIdx.x * 256 + threadIdx.x;
  if (i < KNODES) counts[i] = 0;
}

__global__ void hist_kernel(const int* __restrict__ ei, int* counts) {
  int i = blockIdx.x * 256 + threadIdx.x;
  if (i < NETOT) {
    int dst = (i < NEDGE) ? ei[NEDGE + i] : (i - NEDGE);
    atomicAdd(&counts[dst], 1);
  }
}

__global__ void scan_kernel(const int* __restrict__ counts, int* offs, int* cursor) {
  __shared__ int tmp[1024];
  const int t = threadIdx.x;
  const int base = t * 4;
  int c0 = counts[base], c1 = counts[base + 1], c2 = counts[base + 2], c3 = counts[base + 3];
  const int s = c0 + c1 + c2 + c3;
  tmp[t] = s;
  __syncthreads();
  for (int off = 1; off < 1024; off <<= 1) {
    int v = (t >= off) ? tmp[t - off] : 0;
    __syncthreads();
    tmp[t] += v;
    __syncthreads();
  }
  int o = tmp[t] - s;
  offs[base] = o; cursor[base] = o; o += c0;
  offs[base + 1] = o; cursor[base + 1] = o; o += c1;
  offs[base + 2] = o; cursor[base + 2] = o; o += c2;
  offs[base + 3] = o; cursor[base + 3] = o; o += c3;
  if (t == 1023) offs[KNODES] = o;
}

__global__ void scatter_kernel(const int* __restrict__ ei, int* cursor, int* __restrict__ csr) {
  int i = blockIdx.x * 256 + threadIdx.x;
  if (i < NETOT) {
    int src, dst;
    if (i < NEDGE) { src = ei[i]; dst = ei[NEDGE + i]; }
    else           { src = dst = i - NEDGE; }
    int pos = atomicAdd(&cursor[dst], 1);
    csr[pos] = src;
  }
}

// GAT aggregation: grid (KNODES, 2) — each block handles 16 l's of one dst node.
// Single pass, deferred normalization, 1-edge register prefetch.
#define ECH 32
__global__ __launch_bounds__(256) void gat_aggregate(
    const short* __restrict__ h, const float* __restrict__ as_g, const float* __restrict__ ad_g,
    const int* __restrict__ offs, const int* __restrict__ csr,
    const float* __restrict__ gat_b, float* __restrict__ out) {
  __shared__ float ad_s[16];
  __shared__ float ew[ECH * 17];    // [slot][l_loc], pitch 17
  __shared__ int   srcs[ECH];
  __shared__ float dred[16 * 33];   // [l_loc][slot]
  __shared__ float invd[16];

  const int t = threadIdx.x;
  const int n = blockIdx.x;
  const int l0 = blockIdx.y * 16;
  if (t < 16) ad_s[t] = ad_g[n * SEQL + l0 + t];
  __syncthreads();
  const int beg = offs[n], end = offs[n + 1];

  // phase-A roles: slot s, 2 l's per thread
  const int s = t >> 3, lq = t & 7;
  float dpart0 = 0.f, dpart1 = 0.f;

  // phase-B roles: d pair, wave owns 4 l's
  const int lane2 = t & 63;
  const int lg = t >> 6;
  float acc[4][2];
#pragma unroll
  for (int j = 0; j < 4; ++j) { acc[j][0] = 0.f; acc[j][1] = 0.f; }

  for (int cb = beg; cb < end; cb += ECH) {
    const int cnt = min(ECH, end - cb);
    // ---- phase A: edge weights for our 16 l's
    if (s < cnt) {
      const int src = csr[cb + s];
      if (lq == 0) srcs[s] = src;
      const float2 av = *(const float2*)(as_g + src * SEQL + l0 + lq * 2);
      float v0 = av.x + ad_s[lq * 2];
      v0 = v0 > 0.f ? v0 : 0.2f * v0;
      const float e0 = __expf(v0);
      float v1 = av.y + ad_s[lq * 2 + 1];
      v1 = v1 > 0.f ? v1 : 0.2f * v1;
      const float e1 = __expf(v1);
      ew[s * 17 + lq * 2] = e0;
      ew[s * 17 + lq * 2 + 1] = e1;
      dpart0 += e0; dpart1 += e1;
    }
    __syncthreads();
    // ---- phase B: acc += ew * h[src] with next-edge prefetch
    unsigned cur[4];
    {
      const short* hr = h + (size_t)srcs[0] * (SEQL * DM) + (l0 + lg * 4) * DM + lane2 * 2;
#pragma unroll
      for (int j = 0; j < 4; ++j) cur[j] = *(const unsigned*)(hr + j * DM);
    }
    for (int ss = 0; ss < cnt; ++ss) {
      unsigned nxt[4];
      if (ss + 1 < cnt) {
        const short* hn = h + (size_t)srcs[ss + 1] * (SEQL * DM) + (l0 + lg * 4) * DM + lane2 * 2;
#pragma unroll
        for (int j = 0; j < 4; ++j) nxt[j] = *(const unsigned*)(hn + j * DM);
      }
      const float* ewp = ew + ss * 17 + lg * 4;
#pragma unroll
      for (int j = 0; j < 4; ++j) {
        const float h0 = __uint_as_float(cur[j] << 16);
        const float h1 = __uint_as_float(cur[j] & 0xFFFF0000u);
        const float wgt = ewp[j];
        acc[j][0] += wgt * h0;
        acc[j][1] += wgt * h1;
      }
#pragma unroll
      for (int j = 0; j < 4; ++j) cur[j] = nxt[j];
    }
    __syncthreads();
  }

  // ---- denominator reduce
  dred[(lq * 2) * 33 + s] = dpart0;
  dred[(lq * 2 + 1) * 33 + s] = dpart1;
  __syncthreads();
  if (t < 16) {
    float sum = 0.f;
#pragma unroll
    for (int s2 = 0; s2 < 32; ++s2) sum += dred[t * 33 + s2];
    invd[t] = 1.f / (sum + 1e-16f);
  }
  __syncthreads();

  // ---- write out
  const float b0 = gat_b[lane2 * 2], b1 = gat_b[lane2 * 2 + 1];
#pragma unroll
  for (int j = 0; j < 4; ++j) {
    const int l = l0 + lg * 4 + j;
    const float iv = invd[lg * 4 + j];
    float2 o;
    o.x = acc[j][0] * iv + b0;
    o.y = acc[j][1] * iv + b1;
    *(float2*)(out + (size_t)n * (SEQL * DM) + l * DM + lane2 * 2) = o;
  }
}

extern "C" void kernel_launch(void* const* d_in, const int* in_sizes, int n_in,
                              void* d_out, int out_size, void* d_ws, size_t ws_size,
                              hipStream_t stream) {
  const float* x       = (const float*)d_in[0];
  const int* ei        = (const int*)d_in[1];
  const float* ln1_g   = (const float*)d_in[2];
  const float* ln1_b   = (const float*)d_in[3];
  const float* qkv_w   = (const float*)d_in[4];
  const float* qkv_b   = (const float*)d_in[5];
  const float* out_w   = (const float*)d_in[6];
  const float* out_b   = (const float*)d_in[7];
  const float* ln2_g   = (const float*)d_in[8];
  const float* ln2_b   = (const float*)d_in[9];
  const float* ff1_w   = (const float*)d_in[10];
  const float* ff1_b   = (const float*)d_in[11];
  const float* ff2_w   = (const float*)d_in[12];
  const float* ff2_b   = (const float*)d_in[13];
  const float* gat_w   = (const float*)d_in[14];
  const float* att_src = (const float*)d_in[15];
  const float* att_dst = (const float*)d_in[16];
  const float* gat_b   = (const float*)d_in[17];
  float* out = (float*)d_out;

  // workspace layout
  short* h    = (short*)d_ws;                             // 16777216 shorts (bf16)
  float* as_g = (float*)(h + (size_t)KNODES * SEQL * DM); // 131072 floats
  float* ad_g = as_g + KNODES * SEQL;                     // 131072
  int* counts = (int*)(ad_g + KNODES * SEQL);             // 4096
  int* offs   = counts + KNODES;                          // 4097
  int* cursor = offs + KNODES + 1;                        // 4096
  int* csr    = cursor + KNODES;                          // 69632
  size_t wofs = (size_t)((char*)(csr + NETOT) - (char*)d_ws);
  wofs = (wofs + 15) & ~(size_t)15;
  short* wb = (short*)((char*)d_ws + wofs);               // 212992 shorts
  const short* qkv_wb = wb;
  const short* out_wb = wb + 49152;
  const short* ff1_wb = wb + 65536;
  const short* ff2_wb = wb + 131072;
  const short* gat_wb = wb + 196608;

  cvt_weights<<<208, 256, 0, stream>>>(qkv_w, out_w, ff1_w, ff2_w, gat_w, wb);
  zero_counts<<<(KNODES + 255) / 256, 256, 0, stream>>>(counts);
  hist_kernel<<<(NETOT + 255) / 256, 256, 0, stream>>>(ei, counts);
  scan_kernel<<<1, 1024, 0, stream>>>(counts, offs, cursor);
  scatter_kernel<<<(NETOT + 255) / 256, 256, 0, stream>>>(ei, cursor, csr);
  temporal_kernel<<<KNODES, 512, 0, stream>>>(
      x, ln1_g, ln1_b, qkv_wb, qkv_b, out_wb, out_b, ln2_g, ln2_b,
      ff1_wb, ff1_b, ff2_wb, ff2_b, gat_wb, att_src, att_dst, h, as_g, ad_g);
  gat_aggregate<<<dim3(KNODES, 2), 256, 0, stream>>>(h, as_g, ad_g, offs, csr, gat_b, out);
}

// Round 6
// 357.225 us; speedup vs baseline: 1.2999x; 1.2999x over previous
//
#include <hip/hip_runtime.h>

#define KNODES 4096
#define SEQL 32
#define DM 128
#define DFF 512
#define NEDGE 65536
#define NETOT (NEDGE + KNODES)

typedef float f32x4 __attribute__((ext_vector_type(4)));
typedef short s16x8 __attribute__((ext_vector_type(8)));
typedef short s16x4 __attribute__((ext_vector_type(4)));

#define MFMA16(a, b, c) __builtin_amdgcn_mfma_f32_16x16x32_bf16(a, b, c, 0, 0, 0)

// packed-weight fragment table (frag = 512 shorts = 64 lanes x 16B):
//  qkv: f = tile*4+kt            tiles 0..23   (rows n0=tile*16 of qkv_w[384][128])
//  out: f = 96 + tile*4+kt       tiles 0..7
//  ff1: f = 128 + tile*4+kt      tiles 0..31
//  ff2: f = 256 + ntile*16+kt    ntiles 0..7, kt 0..15 (K=512)
//  gat: f = 384 + tile*4+kt      tiles 0..7
#define F_OUT 96
#define F_FF1 128
#define F_FF2 256
#define F_GAT 384
#define NFRAG 416

__device__ __forceinline__ short f2bf(float f) {
  union { float f; unsigned u; } v; v.f = f;
  unsigned r = (v.u + 0x7FFFu + ((v.u >> 16) & 1u)) >> 16;
  return (short)r;
}

__device__ __forceinline__ float gelu_exact(float v) {
  return 0.5f * v * (1.f + erff(v * 0.70710678118654752440f));
}

// LayerNorm one row-slice: 16 lanes per row, 8 elems per lane.
__device__ __forceinline__ void ln_to_bf16(const float* XF, short* AB,
                                           const float* __restrict__ g,
                                           const float* __restrict__ b,
                                           int r, int cb) {
  const float* xr = XF + r * 132 + cb;
  float v[8]; float s = 0.f, ss = 0.f;
#pragma unroll
  for (int i = 0; i < 8; ++i) { v[i] = xr[i]; s += v[i]; ss += v[i] * v[i]; }
  s += __shfl_xor(s, 1); ss += __shfl_xor(ss, 1);
  s += __shfl_xor(s, 2); ss += __shfl_xor(ss, 2);
  s += __shfl_xor(s, 4); ss += __shfl_xor(ss, 4);
  s += __shfl_xor(s, 8); ss += __shfl_xor(ss, 8);
  const float mean = s * (1.f / 128.f);
  const float var = ss * (1.f / 128.f) - mean * mean;
  const float rs = rsqrtf(var + 1e-5f);
  const float* gp = g + cb; const float* bp = b + cb;
  short o[8];
#pragma unroll
  for (int i = 0; i < 8; ++i) o[i] = f2bf((v[i] - mean) * rs * gp[i] + bp[i]);
  *(s16x8*)(AB + r * 136 + cb) = *(s16x8*)o;
}

// LDS map (bytes), total 53248:
//  XF @0 fp32[32][132]; AB/Sf/Pb @16896; Qb @25600; Kb @34304 (Fb aliases Qb+Kb);
//  Vt @43008 bf16[128][40].
__global__ __launch_bounds__(512, 4) void temporal_kernel(
    const float* __restrict__ x,
    const float* __restrict__ ln1_g, const float* __restrict__ ln1_b,
    const short* __restrict__ wpk, const float* __restrict__ qkv_b,
    const float* __restrict__ out_b,
    const float* __restrict__ ln2_g, const float* __restrict__ ln2_b,
    const float* __restrict__ ff1_b, const float* __restrict__ ff2_b,
    const float* __restrict__ att_src, const float* __restrict__ att_dst,
    short* __restrict__ h_out, float* __restrict__ as_out, float* __restrict__ ad_out) {
  __shared__ __align__(16) char smem[53248];
  float* XF = (float*)smem;
  short* AB = (short*)(smem + 16896);
  float* Sf = (float*)(smem + 16896);
  short* Pb = (short*)(smem + 21504);
  short* Qb = (short*)(smem + 25600);
  short* Kb = (short*)(smem + 34304);
  short* Fb = (short*)(smem + 25600);
  short* Vt = (short*)(smem + 43008);

  const int t = threadIdx.x;
  const int w = t >> 6;                 // 8 waves
  const int lane = t & 63;
  const int q = lane >> 4, c = lane & 15;
  const int n = blockIdx.x;
  const int r16 = t >> 4, cb8 = (t & 15) * 8;

#define WPK(f) ((const s16x8*)(wpk + (size_t)(f) * 512 + lane * 8))

  // ---- QKV weight loads issued immediately (independent of everything)
  s16x8 bwq[3][4];
#pragma unroll
  for (int ii = 0; ii < 3; ++ii)
#pragma unroll
    for (int kt = 0; kt < 4; ++kt)
      bwq[ii][kt] = *WPK((w * 3 + ii) * 4 + kt);

  // ---- load x -> XF (fp32)
  {
#pragma unroll
    for (int i = t; i < 1024; i += 512) {
      const int row = i >> 5, c4i = i & 31;
      *(float4*)(XF + row * 132 + c4i * 4) =
          *(const float4*)(x + (size_t)n * (SEQL * DM) + i * 4);
    }
  }
  __syncthreads();

  // ---- LN1 -> AB
  ln_to_bf16(XF, AB, ln1_g, ln1_b, r16, cb8);
  __syncthreads();

  // ---- QKV GEMM: 24 N-tiles, 3 per wave (weights preloaded).
  {
    s16x8 a[2][4];
#pragma unroll
    for (int mt = 0; mt < 2; ++mt)
#pragma unroll
      for (int kt = 0; kt < 4; ++kt)
        a[mt][kt] = *(const s16x8*)(AB + (mt * 16 + c) * 136 + kt * 32 + q * 8);
#pragma unroll
    for (int ii = 0; ii < 3; ++ii) {
      const int n0 = (w * 3 + ii) * 16;
      f32x4 acc0 = {0.f, 0.f, 0.f, 0.f}, acc1 = {0.f, 0.f, 0.f, 0.f};
#pragma unroll
      for (int kt = 0; kt < 4; ++kt) {
        acc0 = MFMA16(a[0][kt], bwq[ii][kt], acc0);
        acc1 = MFMA16(a[1][kt], bwq[ii][kt], acc1);
      }
      const float bias = qkv_b[n0 + c];
      if (n0 < 128) {            // Q
#pragma unroll
        for (int i = 0; i < 4; ++i) {
          Qb[(q * 4 + i) * 136 + n0 + c] = f2bf(acc0[i] + bias);
          Qb[(16 + q * 4 + i) * 136 + n0 + c] = f2bf(acc1[i] + bias);
        }
      } else if (n0 < 256) {     // K
        const int cc = n0 - 128 + c;
#pragma unroll
        for (int i = 0; i < 4; ++i) {
          Kb[(q * 4 + i) * 136 + cc] = f2bf(acc0[i] + bias);
          Kb[(16 + q * 4 + i) * 136 + cc] = f2bf(acc1[i] + bias);
        }
      } else {                   // V -> Vt transposed
        const int d = n0 - 256 + c;
        s16x4 p0, p1;
#pragma unroll
        for (int i = 0; i < 4; ++i) { p0[i] = f2bf(acc0[i] + bias); p1[i] = f2bf(acc1[i] + bias); }
        *(s16x4*)(Vt + d * 40 + q * 4) = p0;
        *(s16x4*)(Vt + d * 40 + 16 + q * 4) = p1;
      }
    }
  }
  __syncthreads();

  // ---- scores S = Q K^T / sqrt(128). 4 tiles on waves 0-3.
  if (w < 4) {
    const int mt = w & 1, nt = w >> 1;
    s16x8 aq[4], bk[4];
#pragma unroll
    for (int kt = 0; kt < 4; ++kt) {
      aq[kt] = *(const s16x8*)(Qb + (mt * 16 + c) * 136 + kt * 32 + q * 8);
      bk[kt] = *(const s16x8*)(Kb + (nt * 16 + c) * 136 + kt * 32 + q * 8);
    }
    f32x4 acc = {0.f, 0.f, 0.f, 0.f};
#pragma unroll
    for (int kt = 0; kt < 4; ++kt) acc = MFMA16(aq[kt], bk[kt], acc);
#pragma unroll
    for (int i = 0; i < 4; ++i)
      Sf[(mt * 16 + q * 4 + i) * 36 + nt * 16 + c] = acc[i] * 0.08838834764831845f;
  }
  __syncthreads();

  // ---- softmax rows of Sf -> Pb (threads 0..255)
  if (t < 256) {
    const int r8 = t >> 3, c4 = (t & 7) * 4;
    float4 sv = *(const float4*)(Sf + r8 * 36 + c4);
    float mx = fmaxf(fmaxf(sv.x, sv.y), fmaxf(sv.z, sv.w));
    mx = fmaxf(mx, __shfl_xor(mx, 1));
    mx = fmaxf(mx, __shfl_xor(mx, 2));
    mx = fmaxf(mx, __shfl_xor(mx, 4));
    float e0 = expf(sv.x - mx), e1 = expf(sv.y - mx), e2 = expf(sv.z - mx), e3 = expf(sv.w - mx);
    float sum = e0 + e1 + e2 + e3;
    sum += __shfl_xor(sum, 1);
    sum += __shfl_xor(sum, 2);
    sum += __shfl_xor(sum, 4);
    const float inv = 1.f / sum;
    s16x4 pw; pw[0] = f2bf(e0 * inv); pw[1] = f2bf(e1 * inv); pw[2] = f2bf(e2 * inv); pw[3] = f2bf(e3 * inv);
    *(s16x4*)(Pb + r8 * 40 + c4) = pw;
  }
  __syncthreads();

  // ---- attn = P @ V (1 d-tile per wave) + early proj-weight loads
  s16x8 bwp[4];
  {
#pragma unroll
    for (int kt = 0; kt < 4; ++kt) bwp[kt] = *WPK(F_OUT + w * 4 + kt);
    s16x8 ap0 = *(const s16x8*)(Pb + c * 40 + q * 8);
    s16x8 ap1 = *(const s16x8*)(Pb + (16 + c) * 40 + q * 8);
    const int d0 = w * 16;
    s16x8 bv = *(const s16x8*)(Vt + (d0 + c) * 40 + q * 8);
    f32x4 acc0 = {0.f, 0.f, 0.f, 0.f}, acc1 = {0.f, 0.f, 0.f, 0.f};
    acc0 = MFMA16(ap0, bv, acc0);
    acc1 = MFMA16(ap1, bv, acc1);
#pragma unroll
    for (int i = 0; i < 4; ++i) {
      Qb[(q * 4 + i) * 136 + d0 + c] = f2bf(acc0[i]);
      Qb[(16 + q * 4 + i) * 136 + d0 + c] = f2bf(acc1[i]);
    }
  }
  __syncthreads();

  // ---- proj: XF += attn @ out_w^T + out_b (weights preloaded)
  {
    s16x8 aa[2][4];
#pragma unroll
    for (int mt = 0; mt < 2; ++mt)
#pragma unroll
      for (int kt = 0; kt < 4; ++kt)
        aa[mt][kt] = *(const s16x8*)(Qb + (mt * 16 + c) * 136 + kt * 32 + q * 8);
    const int n0 = w * 16;
    f32x4 acc0 = {0.f, 0.f, 0.f, 0.f}, acc1 = {0.f, 0.f, 0.f, 0.f};
#pragma unroll
    for (int kt = 0; kt < 4; ++kt) {
      acc0 = MFMA16(aa[0][kt], bwp[kt], acc0);
      acc1 = MFMA16(aa[1][kt], bwp[kt], acc1);
    }
    const float bias = out_b[n0 + c];
#pragma unroll
    for (int i = 0; i < 4; ++i) {
      XF[(q * 4 + i) * 132 + n0 + c] += acc0[i] + bias;
      XF[(16 + q * 4 + i) * 132 + n0 + c] += acc1[i] + bias;
    }
  }
  __syncthreads();

  // ---- LN2 -> AB
  ln_to_bf16(XF, AB, ln2_g, ln2_b, r16, cb8);
  __syncthreads();

  // ---- FFN: two 256-col chunks; all weight frags hoisted per chunk.
  {
    s16x8 af[2][4];
#pragma unroll
    for (int mt = 0; mt < 2; ++mt)
#pragma unroll
      for (int kt = 0; kt < 4; ++kt)
        af[mt][kt] = *(const s16x8*)(AB + (mt * 16 + c) * 136 + kt * 32 + q * 8);
    f32x4 facc0 = {0.f, 0.f, 0.f, 0.f}, facc1 = {0.f, 0.f, 0.f, 0.f};

    for (int ch = 0; ch < 2; ++ch) {
      s16x8 bw1[2][4], bw2[8];
#pragma unroll
      for (int ii = 0; ii < 2; ++ii)
#pragma unroll
        for (int kt = 0; kt < 4; ++kt)
          bw1[ii][kt] = *WPK(F_FF1 + (ch * 16 + w * 2 + ii) * 4 + kt);
#pragma unroll
      for (int kt = 0; kt < 8; ++kt)
        bw2[kt] = *WPK(F_FF2 + w * 16 + ch * 8 + kt);

#pragma unroll
      for (int ii = 0; ii < 2; ++ii) {
        const int ntl = w * 2 + ii;
        const int n0g = ch * 256 + ntl * 16;
        f32x4 acc0 = {0.f, 0.f, 0.f, 0.f}, acc1 = {0.f, 0.f, 0.f, 0.f};
#pragma unroll
        for (int kt = 0; kt < 4; ++kt) {
          acc0 = MFMA16(af[0][kt], bw1[ii][kt], acc0);
          acc1 = MFMA16(af[1][kt], bw1[ii][kt], acc1);
        }
        const float bias = ff1_b[n0g + c];
#pragma unroll
        for (int i = 0; i < 4; ++i) {
          Fb[(q * 4 + i) * 264 + ntl * 16 + c] = f2bf(gelu_exact(acc0[i] + bias));
          Fb[(16 + q * 4 + i) * 264 + ntl * 16 + c] = f2bf(gelu_exact(acc1[i] + bias));
        }
      }
      __syncthreads();
#pragma unroll
      for (int kt = 0; kt < 8; ++kt) {
        s16x8 a0 = *(const s16x8*)(Fb + c * 264 + kt * 32 + q * 8);
        s16x8 a1 = *(const s16x8*)(Fb + (16 + c) * 264 + kt * 32 + q * 8);
        facc0 = MFMA16(a0, bw2[kt], facc0);
        facc1 = MFMA16(a1, bw2[kt], facc1);
      }
      __syncthreads();
    }
    // epilogue fused with xt->bf16: AB = bf16(XF + facc + ff2_b)
    {
      const int n0 = w * 16;
      const float bias = ff2_b[n0 + c];
#pragma unroll
      for (int i = 0; i < 4; ++i) {
        const int r0 = q * 4 + i, r1 = 16 + q * 4 + i;
        AB[r0 * 136 + n0 + c] = f2bf(XF[r0 * 132 + n0 + c] + facc0[i] + bias);
        AB[r1 * 136 + n0 + c] = f2bf(XF[r1 * 132 + n0 + c] + facc1[i] + bias);
      }
    }
  }
  // early GAT weight loads (independent of the barrier below)
  s16x8 bwg[4];
#pragma unroll
  for (int kt = 0; kt < 4; ++kt) bwg[kt] = *WPK(F_GAT + w * 4 + kt);
  __syncthreads();

  // ---- GAT projection h = xt @ gat_w^T -> XF (fp32); h_out written coalesced below
  {
    s16x8 ag[2][4];
#pragma unroll
    for (int mt = 0; mt < 2; ++mt)
#pragma unroll
      for (int kt = 0; kt < 4; ++kt)
        ag[mt][kt] = *(const s16x8*)(AB + (mt * 16 + c) * 136 + kt * 32 + q * 8);
    const int n0 = w * 16;
    f32x4 acc0 = {0.f, 0.f, 0.f, 0.f}, acc1 = {0.f, 0.f, 0.f, 0.f};
#pragma unroll
    for (int kt = 0; kt < 4; ++kt) {
      acc0 = MFMA16(ag[0][kt], bwg[kt], acc0);
      acc1 = MFMA16(ag[1][kt], bwg[kt], acc1);
    }
#pragma unroll
    for (int i = 0; i < 4; ++i) {
      const int r0 = q * 4 + i, r1 = 16 + q * 4 + i;
      XF[r0 * 132 + n0 + c] = acc0[i];
      XF[r1 * 132 + n0 + c] = acc1[i];
    }
  }
  __syncthreads();

  // ---- h_out: coalesced bf16 write (full 128B lines), 16B per thread
  {
    const int row = t >> 4;
    const float* xr = XF + row * 132 + cb8;
    short o[8];
#pragma unroll
    for (int i = 0; i < 8; ++i) o[i] = f2bf(xr[i]);
    *(s16x8*)(h_out + ((size_t)n * SEQL + row) * DM + cb8) = *(s16x8*)o;
  }

  // ---- a_s / a_d
  if (t < 64) {
    const int row = t & 31;
    const float* vec = (t < 32) ? att_src : att_dst;
    const float* hr = XF + row * 132;
    float s = 0.f;
#pragma unroll
    for (int d = 0; d < DM; d += 4)
      s += hr[d] * vec[d] + hr[d + 1] * vec[d + 1] + hr[d + 2] * vec[d + 2] + hr[d + 3] * vec[d + 3];
    if (t < 32) as_out[n * SEQL + row] = s;
    else        ad_out[n * SEQL + row] = s;
  }
}

// fp32 -> bf16 tile-packed weight conversion: wpk[frag][lane][8].
__global__ void cvt_weights(const float* __restrict__ qkv_w, const float* __restrict__ out_w,
                            const float* __restrict__ ff1_w, const float* __restrict__ ff2_w,
                            const float* __restrict__ gat_w, short* __restrict__ wpk) {
  const int u = blockIdx.x * 256 + threadIdx.x;
  if (u >= NFRAG * 64) return;
  const int f = u >> 6, lane = u & 63;
  const int q = lane >> 4, c = lane & 15;
  const float* src; int row, kt, ld;
  if (f < F_OUT)       { src = qkv_w; ld = 128; int g = f;         row = (g >> 2) * 16 + c; kt = g & 3; }
  else if (f < F_FF1)  { src = out_w; ld = 128; int g = f - F_OUT; row = (g >> 2) * 16 + c; kt = g & 3; }
  else if (f < F_FF2)  { src = ff1_w; ld = 128; int g = f - F_FF1; row = (g >> 2) * 16 + c; kt = g & 3; }
  else if (f < F_GAT)  { src = ff2_w; ld = 512; int g = f - F_FF2; row = (g >> 4) * 16 + c; kt = g & 15; }
  else                 { src = gat_w; ld = 128; int g = f - F_GAT; row = (g >> 2) * 16 + c; kt = g & 3; }
  const float* p = src + row * ld + kt * 32 + q * 8;
  const float4 v0 = *(const float4*)p;
  const float4 v1 = *(const float4*)(p + 4);
  s16x8 o;
  o[0] = f2bf(v0.x); o[1] = f2bf(v0.y); o[2] = f2bf(v0.z); o[3] = f2bf(v0.w);
  o[4] = f2bf(v1.x); o[5] = f2bf(v1.y); o[6] = f2bf(v1.z); o[7] = f2bf(v1.w);
  *(s16x8*)(wpk + (size_t)f * 512 + lane * 8) = o;
}

__global__ void zero_counts(int* counts) {
  int i = blockIdx.x * 256 + threadIdx.x;
  if (i < KNODES) counts[i] = 0;
}

__global__ void hist_kernel(const int* __restrict__ ei, int* counts) {
  int i = blockIdx.x * 256 + threadIdx.x;
  if (i < NETOT) {
    int dst = (i < NEDGE) ? ei[NEDGE + i] : (i - NEDGE);
    atomicAdd(&counts[dst], 1);
  }
}

__global__ void scan_kernel(const int* __restrict__ counts, int* offs, int* cursor) {
  __shared__ int tmp[1024];
  const int t = threadIdx.x;
  const int base = t * 4;
  int c0 = counts[base], c1 = counts[base + 1], c2 = counts[base + 2], c3 = counts[base + 3];
  const int s = c0 + c1 + c2 + c3;
  tmp[t] = s;
  __syncthreads();
  for (int off = 1; off < 1024; off <<= 1) {
    int v = (t >= off) ? tmp[t - off] : 0;
    __syncthreads();
    tmp[t] += v;
    __syncthreads();
  }
  int o = tmp[t] - s;
  offs[base] = o; cursor[base] = o; o += c0;
  offs[base + 1] = o; cursor[base + 1] = o; o += c1;
  offs[base + 2] = o; cursor[base + 2] = o; o += c2;
  offs[base + 3] = o; cursor[base + 3] = o; o += c3;
  if (t == 1023) offs[KNODES] = o;
}

__global__ void scatter_kernel(const int* __restrict__ ei, int* cursor, int* __restrict__ csr) {
  int i = blockIdx.x * 256 + threadIdx.x;
  if (i < NETOT) {
    int src, dst;
    if (i < NEDGE) { src = ei[i]; dst = ei[NEDGE + i]; }
    else           { src = dst = i - NEDGE; }
    int pos = atomicAdd(&cursor[dst], 1);
    csr[pos] = src;
  }
}

// GAT aggregation: grid (KNODES, 2); single pass, deferred norm, prefetch-1.
#define ECH 32
__global__ __launch_bounds__(256) void gat_aggregate(
    const short* __restrict__ h, const float* __restrict__ as_g, const float* __restrict__ ad_g,
    const int* __restrict__ offs, const int* __restrict__ csr,
    const float* __restrict__ gat_b, float* __restrict__ out) {
  __shared__ float ad_s[16];
  __shared__ float ew[ECH * 17];
  __shared__ int   srcs[ECH];
  __shared__ float dred[16 * 33];
  __shared__ float invd[16];

  const int t = threadIdx.x;
  const int n = blockIdx.x;
  const int l0 = blockIdx.y * 16;
  if (t < 16) ad_s[t] = ad_g[n * SEQL + l0 + t];
  __syncthreads();
  const int beg = offs[n], end = offs[n + 1];

  const int s = t >> 3, lq = t & 7;
  float dpart0 = 0.f, dpart1 = 0.f;

  const int lane2 = t & 63;
  const int lg = t >> 6;
  float acc[4][2];
#pragma unroll
  for (int j = 0; j < 4; ++j) { acc[j][0] = 0.f; acc[j][1] = 0.f; }

  for (int cb = beg; cb < end; cb += ECH) {
    const int cnt = min(ECH, end - cb);
    if (s < cnt) {
      const int src = csr[cb + s];
      if (lq == 0) srcs[s] = src;
      const float2 av = *(const float2*)(as_g + src * SEQL + l0 + lq * 2);
      float v0 = av.x + ad_s[lq * 2];
      v0 = v0 > 0.f ? v0 : 0.2f * v0;
      const float e0 = __expf(v0);
      float v1 = av.y + ad_s[lq * 2 + 1];
      v1 = v1 > 0.f ? v1 : 0.2f * v1;
      const float e1 = __expf(v1);
      ew[s * 17 + lq * 2] = e0;
      ew[s * 17 + lq * 2 + 1] = e1;
      dpart0 += e0; dpart1 += e1;
    }
    __syncthreads();
    unsigned cur[4];
    {
      const short* hr = h + (size_t)srcs[0] * (SEQL * DM) + (l0 + lg * 4) * DM + lane2 * 2;
#pragma unroll
      for (int j = 0; j < 4; ++j) cur[j] = *(const unsigned*)(hr + j * DM);
    }
    for (int ss = 0; ss < cnt; ++ss) {
      unsigned nxt[4];
      if (ss + 1 < cnt) {
        const short* hn = h + (size_t)srcs[ss + 1] * (SEQL * DM) + (l0 + lg * 4) * DM + lane2 * 2;
#pragma unroll
        for (int j = 0; j < 4; ++j) nxt[j] = *(const unsigned*)(hn + j * DM);
      }
      const float* ewp = ew + ss * 17 + lg * 4;
#pragma unroll
      for (int j = 0; j < 4; ++j) {
        const float h0 = __uint_as_float(cur[j] << 16);
        const float h1 = __uint_as_float(cur[j] & 0xFFFF0000u);
        const float wgt = ewp[j];
        acc[j][0] += wgt * h0;
        acc[j][1] += wgt * h1;
      }
#pragma unroll
      for (int j = 0; j < 4; ++j) cur[j] = nxt[j];
    }
    __syncthreads();
  }

  dred[(lq * 2) * 33 + s] = dpart0;
  dred[(lq * 2 + 1) * 33 + s] = dpart1;
  __syncthreads();
  if (t < 16) {
    float sum = 0.f;
#pragma unroll
    for (int s2 = 0; s2 < 32; ++s2) sum += dred[t * 33 + s2];
    invd[t] = 1.f / (sum + 1e-16f);
  }
  __syncthreads();

  const float b0 = gat_b[lane2 * 2], b1 = gat_b[lane2 * 2 + 1];
#pragma unroll
  for (int j = 0; j < 4; ++j) {
    const int l = l0 + lg * 4 + j;
    const float iv = invd[lg * 4 + j];
    float2 o;
    o.x = acc[j][0] * iv + b0;
    o.y = acc[j][1] * iv + b1;
    *(float2*)(out + (size_t)n * (SEQL * DM) + l * DM + lane2 * 2) = o;
  }
}

extern "C" void kernel_launch(void* const* d_in, const int* in_sizes, int n_in,
                              void* d_out, int out_size, void* d_ws, size_t ws_size,
                              hipStream_t stream) {
  const float* x       = (const float*)d_in[0];
  const int* ei        = (const int*)d_in[1];
  const float* ln1_g   = (const float*)d_in[2];
  const float* ln1_b   = (const float*)d_in[3];
  const float* qkv_w   = (const float*)d_in[4];
  const float* qkv_b   = (const float*)d_in[5];
  const float* out_w   = (const float*)d_in[6];
  const float* out_b   = (const float*)d_in[7];
  const float* ln2_g   = (const float*)d_in[8];
  const float* ln2_b   = (const float*)d_in[9];
  const float* ff1_w   = (const float*)d_in[10];
  const float* ff1_b   = (const float*)d_in[11];
  const float* ff2_w   = (const float*)d_in[12];
  const float* ff2_b   = (const float*)d_in[13];
  const float* gat_w   = (const float*)d_in[14];
  const float* att_src = (const float*)d_in[15];
  const float* att_dst = (const float*)d_in[16];
  const float* gat_b   = (const float*)d_in[17];
  float* out = (float*)d_out;

  short* h    = (short*)d_ws;                             // 16777216 shorts (bf16)
  float* as_g = (float*)(h + (size_t)KNODES * SEQL * DM); // 131072 floats
  float* ad_g = as_g + KNODES * SEQL;                     // 131072
  int* counts = (int*)(ad_g + KNODES * SEQL);             // 4096
  int* offs   = counts + KNODES;                          // 4097
  int* cursor = offs + KNODES + 1;                        // 4096
  int* csr    = cursor + KNODES;                          // 69632
  size_t wofs = (size_t)((char*)(csr + NETOT) - (char*)d_ws);
  wofs = (wofs + 1023) & ~(size_t)1023;
  short* wpk = (short*)((char*)d_ws + wofs);              // 416*512 shorts

  cvt_weights<<<(NFRAG * 64 + 255) / 256, 256, 0, stream>>>(qkv_w, out_w, ff1_w, ff2_w, gat_w, wpk);
  zero_counts<<<(KNODES + 255) / 256, 256, 0, stream>>>(counts);
  hist_kernel<<<(NETOT + 255) / 256, 256, 0, stream>>>(ei, counts);
  scan_kernel<<<1, 1024, 0, stream>>>(counts, offs, cursor);
  scatter_kernel<<<(NETOT + 255) / 256, 256, 0, stream>>>(ei, cursor, csr);
  temporal_kernel<<<KNODES, 512, 0, stream>>>(
      x, ln1_g, ln1_b, wpk, qkv_b, out_b, ln2_g, ln2_b,
      ff1_b, ff2_b, att_src, att_dst, h, as_g, ad_g);
  gat_aggregate<<<dim3(KNODES, 2), 256, 0, stream>>>(h, as_g, ad_g, offs, csr, gat_b, out);
}